// Round 1
// 269.101 us; speedup vs baseline: 1.3022x; 1.3022x over previous
//
#include <hip/hip_runtime.h>
#include <hip/hip_bf16.h>

// Problem: B=2, C=64, H=W=96 -> M=N=9216
//   scores[b,m,n] = sum_c yi[b,c,m]*pi[b,c,n] ; weight = softmax over m
//   out[b,c,n]    = sum_m yi[b,c,m]*weight[b,m,n]
// == flash attention with Q=pi (queries n), K=V=yi (keys m), head dim 64.
//
// R1: split-K (flash-decoding) over the key axis. Baseline grid was 192 blocks
// on 256 CUs (Occupancy 13%, MfmaUtil 8.5%, HBM 0.8% -> latency-bound).
// S=4 splits -> 768 blocks = 3 resident blocks/CU (LDS-capped at 41.5KB each),
// partial (O, m, l) to workspace + tiny combine kernel.

#define CC 64
#define MM 9216
#define BB 2
#define NBLK 96          // query columns per workgroup (6 waves x 16)
#define WAVES 6
#define MTILE 64         // keys per tile
#define NT (MM / MTILE)  // 144
#define LDP 72           // padded LDS row (72 bf16 = 144 B, breaks bank conflicts)

typedef __bf16 bf16x8 __attribute__((ext_vector_type(8)));
typedef float f32x4 __attribute__((ext_vector_type(4)));

template<bool FINAL>
__global__ __launch_bounds__(WAVES * 64)
void attn_flash_split(const float* __restrict__ yi, const float* __restrict__ pi,
                      float* __restrict__ out, float* __restrict__ opart,
                      float* __restrict__ mlpart, const int nsplits)
{
    __shared__ __align__(16) __bf16 k_hi[MTILE][LDP];
    __shared__ __align__(16) __bf16 k_lo[MTILE][LDP];
    __shared__ __align__(16) __bf16 v_sm[CC][LDP];
    __shared__ __align__(16) __bf16 p_sm[WAVES][16][LDP];

    const int tid  = threadIdx.x;
    const int lane = tid & 63;
    const int wave = tid >> 6;     // 0..5
    const int ln   = lane & 15;    // MFMA col / row-within-16
    const int lg   = lane >> 4;    // 0..3 lane group

    const int b     = blockIdx.z;
    const int split = blockIdx.y;
    const int tpb   = NT / nsplits;        // tiles per split
    const int t0    = split * tpb;
    const int n0    = blockIdx.x * NBLK;
    const int n_glob = n0 + wave * 16 + ln;

    // ---- Q fragments (hi/lo split) held in registers, loaded once ----
    bf16x8 qh[2], ql[2];
    {
        const float* qb = pi + (size_t)b * CC * MM + n_glob;
        #pragma unroll
        for (int ks = 0; ks < 2; ++ks) {
            #pragma unroll
            for (int j = 0; j < 8; ++j) {
                const int c = ks * 32 + lg * 8 + j;
                const float f = qb[(size_t)c * MM];
                const __bf16 hi = (__bf16)f;
                qh[ks][j] = hi;
                ql[ks][j] = (__bf16)(f - (float)hi);
            }
        }
    }

    f32x4 o[4];
    #pragma unroll
    for (int ct = 0; ct < 4; ++ct) o[ct] = (f32x4){0.f, 0.f, 0.f, 0.f};
    float run_max = -INFINITY;
    float run_l   = 0.f;

    const float* yib = yi + (size_t)b * CC * MM;

    // ---- stage first tile of this split ----
    {
        const int m0 = t0 * MTILE;
        for (int i = tid; i < (MTILE * CC) / 4; i += WAVES * 64) {
            const int c  = i >> 4;
            const int m4 = (i & 15) * 4;
            const float4 v = *reinterpret_cast<const float4*>(yib + (size_t)c * MM + m0 + m4);
            const float fv[4] = {v.x, v.y, v.z, v.w};
            #pragma unroll
            for (int j = 0; j < 4; ++j) {
                const __bf16 hi = (__bf16)fv[j];
                k_hi[m4 + j][c] = hi;
                k_lo[m4 + j][c] = (__bf16)(fv[j] - (float)hi);
                v_sm[c][m4 + j] = hi;
            }
        }
    }
    __syncthreads();

    for (int it = 0; it < tpb; ++it) {
        // ---- QK^T: S[m(64)][n(16)] per wave, split-bf16 (3 MFMAs) ----
        f32x4 s[4];
        #pragma unroll
        for (int mt = 0; mt < 4; ++mt) s[mt] = (f32x4){0.f, 0.f, 0.f, 0.f};
        #pragma unroll
        for (int ks = 0; ks < 2; ++ks) {
            const bf16x8 bh = qh[ks];
            const bf16x8 bl = ql[ks];
            #pragma unroll
            for (int mt = 0; mt < 4; ++mt) {
                const bf16x8 ah = *reinterpret_cast<const bf16x8*>(&k_hi[mt * 16 + ln][ks * 32 + lg * 8]);
                const bf16x8 al = *reinterpret_cast<const bf16x8*>(&k_lo[mt * 16 + ln][ks * 32 + lg * 8]);
                s[mt] = __builtin_amdgcn_mfma_f32_16x16x32_bf16(ah, bh, s[mt], 0, 0, 0);
                s[mt] = __builtin_amdgcn_mfma_f32_16x16x32_bf16(ah, bl, s[mt], 0, 0, 0);
                s[mt] = __builtin_amdgcn_mfma_f32_16x16x32_bf16(al, bh, s[mt], 0, 0, 0);
            }
        }

        // ---- online softmax over m (column reduce across 4 lane groups) ----
        float tmax = -INFINITY;
        #pragma unroll
        for (int mt = 0; mt < 4; ++mt)
            #pragma unroll
            for (int r = 0; r < 4; ++r) tmax = fmaxf(tmax, s[mt][r]);
        tmax = fmaxf(tmax, __shfl_xor(tmax, 16));
        tmax = fmaxf(tmax, __shfl_xor(tmax, 32));

        const float mnew = fmaxf(run_max, tmax);
        const float corr = __expf(run_max - mnew);   // 0 on first iter

        float psum = 0.f;
        #pragma unroll
        for (int mt = 0; mt < 4; ++mt) {
            #pragma unroll
            for (int r = 0; r < 4; ++r) {
                const float pv = __expf(s[mt][r] - mnew);
                psum += pv;
                p_sm[wave][ln][mt * 16 + lg * 4 + r] = (__bf16)pv;
            }
        }
        psum += __shfl_xor(psum, 16);
        psum += __shfl_xor(psum, 32);
        run_l   = run_l * corr + psum;
        run_max = mnew;

        #pragma unroll
        for (int ct = 0; ct < 4; ++ct) o[ct] *= corr;

        // ---- PV: O[c(64)][n(16)] += V[c][m] * P[m][n] ----
        // same-wave LDS write->read: DS ops complete in order within a wave
        #pragma unroll
        for (int ks = 0; ks < 2; ++ks) {
            const bf16x8 bp = *reinterpret_cast<const bf16x8*>(&p_sm[wave][ln][ks * 32 + lg * 8]);
            #pragma unroll
            for (int ct = 0; ct < 4; ++ct) {
                const bf16x8 av = *reinterpret_cast<const bf16x8*>(&v_sm[ct * 16 + ln][ks * 32 + lg * 8]);
                o[ct] = __builtin_amdgcn_mfma_f32_16x16x32_bf16(av, bp, o[ct], 0, 0, 0);
            }
        }

        __syncthreads();   // all waves done reading k_hi/k_lo/v_sm
        if (it + 1 < tpb) {
            const int m0 = (t0 + it + 1) * MTILE;
            for (int i = tid; i < (MTILE * CC) / 4; i += WAVES * 64) {
                const int c  = i >> 4;
                const int m4 = (i & 15) * 4;
                const float4 v = *reinterpret_cast<const float4*>(yib + (size_t)c * MM + m0 + m4);
                const float fv[4] = {v.x, v.y, v.z, v.w};
                #pragma unroll
                for (int j = 0; j < 4; ++j) {
                    const __bf16 hi = (__bf16)fv[j];
                    k_hi[m4 + j][c] = hi;
                    k_lo[m4 + j][c] = (__bf16)(fv[j] - (float)hi);
                    v_sm[c][m4 + j] = hi;
                }
            }
        }
        __syncthreads();   // staged tile visible
    }

    // ---- epilogue ----
    if (FINAL) {
        const float inv = 1.f / run_l;
        #pragma unroll
        for (int ct = 0; ct < 4; ++ct) {
            #pragma unroll
            for (int r = 0; r < 4; ++r) {
                const int c = ct * 16 + lg * 4 + r;
                out[((size_t)b * CC + c) * MM + n_glob] = o[ct][r] * inv;
            }
        }
    } else {
        // unnormalized partial O + (running max, running sum) per query column
        const size_t pbase = (size_t)(b * nsplits + split) * CC * MM;
        #pragma unroll
        for (int ct = 0; ct < 4; ++ct) {
            #pragma unroll
            for (int r = 0; r < 4; ++r) {
                const int c = ct * 16 + lg * 4 + r;
                opart[pbase + (size_t)c * MM + n_glob] = o[ct][r];
            }
        }
        if (lg == 0) {   // run_max/run_l uniform across the 4 lane groups
            const size_t mb = ((size_t)(b * nsplits + split) * MM + n_glob) * 2;
            mlpart[mb]     = run_max;
            mlpart[mb + 1] = run_l;
        }
    }
}

// out[b,c,n] = sum_s Opart[b,s,c,n] * e^{m_s - M} / sum_s l_s * e^{m_s - M}
__global__ __launch_bounds__(256)
void attn_reduce(const float* __restrict__ opart, const float* __restrict__ mlpart,
                 float* __restrict__ out, const int nsplits)
{
    const int gid = blockIdx.x * 256 + threadIdx.x;     // (b*CC + c)*MM + n
    if (gid >= BB * CC * MM) return;
    const int n  = gid % MM;
    const int bc = gid / MM;
    const int b  = bc / CC;
    const int c  = bc - b * CC;

    float ms[8], ls[8];
    float Mx = -INFINITY;
    for (int s = 0; s < nsplits; ++s) {
        const size_t mb = ((size_t)(b * nsplits + s) * MM + n) * 2;
        ms[s] = mlpart[mb];
        ls[s] = mlpart[mb + 1];
        Mx = fmaxf(Mx, ms[s]);
    }
    float L = 0.f;
    for (int s = 0; s < nsplits; ++s) {
        ms[s] = __expf(ms[s] - Mx);
        L += ls[s] * ms[s];
    }
    float acc = 0.f;
    for (int s = 0; s < nsplits; ++s)
        acc += opart[((size_t)(b * nsplits + s) * CC + c) * MM + n] * ms[s];
    out[gid] = acc / L;
}

extern "C" void kernel_launch(void* const* d_in, const int* in_sizes, int n_in,
                              void* d_out, int out_size, void* d_ws, size_t ws_size,
                              hipStream_t stream) {
    const float* yi = (const float*)d_in[0];   // feature_yi
    const float* pi = (const float*)d_in[1];   // feature_pi
    float* out = (float*)d_out;

    // workspace need for S splits: O partials (f32) + (m,l) per (b,s,n)
    auto need = [](int s) -> size_t {
        return (size_t)BB * s * CC * MM * 4 + (size_t)BB * s * MM * 2 * 4;
    };

    int S = 0;
    if (d_ws && ws_size >= need(4))      S = 4;   // 768 blocks = 3/CU resident
    else if (d_ws && ws_size >= need(2)) S = 2;   // 384 blocks

    if (S == 0) {
        // fallback: original single-kernel path
        dim3 grid(MM / NBLK, 1, BB);
        attn_flash_split<true><<<grid, dim3(WAVES * 64), 0, stream>>>(
            yi, pi, out, nullptr, nullptr, 1);
    } else {
        float* opart  = (float*)d_ws;
        float* mlpart = opart + (size_t)BB * S * CC * MM;
        dim3 grid(MM / NBLK, S, BB);
        attn_flash_split<false><<<grid, dim3(WAVES * 64), 0, stream>>>(
            yi, pi, out, opart, mlpart, S);
        const int total = BB * CC * MM;
        attn_reduce<<<dim3((total + 255) / 256), dim3(256), 0, stream>>>(
            opart, mlpart, out, S);
    }
}

// Round 2
// 186.632 us; speedup vs baseline: 1.8777x; 1.4419x over previous
//
#include <hip/hip_runtime.h>
#include <hip/hip_bf16.h>

// Problem: B=2, C=64, H=W=96 -> M=N=9216
//   scores[b,m,n] = sum_c yi[b,c,m]*pi[b,c,n] ; weight = softmax over m
//   out[b,c,n]    = sum_m yi[b,c,m]*weight[b,m,n]
// == flash attention with Q=pi (queries n), K=V=yi (keys m), head dim 64.
//
// R2: kill LDS bank conflicts (SQ_LDS_BANK_CONFLICT was 6.9e7 ~= 42% of
// runtime in serialized LDS cycles). All LDS arrays use row-XOR swizzle
//   col_stored = col ^ (s(row)<<3),  s(row) = ((row>>1)^(row>>4))&7
// which makes the transpose-writes conflict-free while keeping the b128
// fragment reads at the 8-cycle wave64 minimum (bank pattern enumerated by
// hand). v_sm and p_sm writes vectorized to ds_write_b64. Row stride drops
// 72->64 (swizzle replaces padding): LDS 41.4->36.9 KB -> 4 blocks/CU, so
// splits bumped to S=8 (grid 1536 = 6/CU balanced) when workspace allows.

#define CC 64
#define MM 9216
#define BB 2
#define NBLK 96          // query columns per workgroup (6 waves x 16)
#define WAVES 6
#define MTILE 64         // keys per tile
#define NT (MM / MTILE)  // 144

typedef __bf16 bf16x8 __attribute__((ext_vector_type(8)));
typedef __bf16 bf16x4 __attribute__((ext_vector_type(4)));
typedef float f32x4 __attribute__((ext_vector_type(4)));

// row-XOR swizzle: spreads the 16-byte chunks of each row across banks.
__device__ __forceinline__ int swz(int row) { return ((row >> 1) ^ (row >> 4)) & 7; }

template<bool FINAL>
__global__ __launch_bounds__(WAVES * 64)
void attn_flash_split(const float* __restrict__ yi, const float* __restrict__ pi,
                      float* __restrict__ out, float* __restrict__ opart,
                      float* __restrict__ mlpart, const int nsplits)
{
    __shared__ __align__(16) __bf16 k_hi[MTILE][64];   // [m][c^swz(m)<<3]
    __shared__ __align__(16) __bf16 k_lo[MTILE][64];
    __shared__ __align__(16) __bf16 v_sm[CC][64];      // [c][m^swz(c)<<3]
    __shared__ __align__(16) __bf16 p_sm[WAVES][16][64]; // [w][n][m^((n>>1)<<3)]

    const int tid  = threadIdx.x;
    const int lane = tid & 63;
    const int wave = tid >> 6;     // 0..5
    const int ln   = lane & 15;    // MFMA col / row-within-16
    const int lg   = lane >> 4;    // 0..3 lane group

    const int b     = blockIdx.z;
    const int split = blockIdx.y;
    const int tpb   = NT / nsplits;        // tiles per split
    const int t0    = split * tpb;
    const int n0    = blockIdx.x * NBLK;
    const int n_glob = n0 + wave * 16 + ln;

    // ---- Q fragments (hi/lo split) held in registers, loaded once ----
    bf16x8 qh[2], ql[2];
    {
        const float* qb = pi + (size_t)b * CC * MM + n_glob;
        #pragma unroll
        for (int ks = 0; ks < 2; ++ks) {
            #pragma unroll
            for (int j = 0; j < 8; ++j) {
                const int c = ks * 32 + lg * 8 + j;
                const float f = qb[(size_t)c * MM];
                const __bf16 hi = (__bf16)f;
                qh[ks][j] = hi;
                ql[ks][j] = (__bf16)(f - (float)hi);
            }
        }
    }

    f32x4 o[4];
    #pragma unroll
    for (int ct = 0; ct < 4; ++ct) o[ct] = (f32x4){0.f, 0.f, 0.f, 0.f};
    float run_max = -INFINITY;
    float run_l   = 0.f;

    const float* yib = yi + (size_t)b * CC * MM;

    // ---- stage first tile of this split ----
    {
        const int m0 = t0 * MTILE;
        for (int i = tid; i < (MTILE * CC) / 4; i += WAVES * 64) {
            const int c  = i >> 4;
            const int m4 = (i & 15) * 4;
            const float4 v = *reinterpret_cast<const float4*>(yib + (size_t)c * MM + m0 + m4);
            const float fv[4] = {v.x, v.y, v.z, v.w};
            bf16x4 vv;
            #pragma unroll
            for (int j = 0; j < 4; ++j) {
                const int m  = m4 + j;
                const int sx = swz(m) << 3;
                const __bf16 hi = (__bf16)fv[j];
                k_hi[m][c ^ sx] = hi;
                k_lo[m][c ^ sx] = (__bf16)(fv[j] - (float)hi);
                vv[j] = hi;
            }
            *reinterpret_cast<bf16x4*>(&v_sm[c][m4 ^ (swz(c) << 3)]) = vv;
        }
    }
    __syncthreads();

    for (int it = 0; it < tpb; ++it) {
        // ---- QK^T: S[m(64)][n(16)] per wave, split-bf16 (3 MFMAs) ----
        f32x4 s[4];
        #pragma unroll
        for (int mt = 0; mt < 4; ++mt) s[mt] = (f32x4){0.f, 0.f, 0.f, 0.f};
        #pragma unroll
        for (int ks = 0; ks < 2; ++ks) {
            const bf16x8 bh = qh[ks];
            const bf16x8 bl = ql[ks];
            #pragma unroll
            for (int mt = 0; mt < 4; ++mt) {
                const int col = (ks * 32 + lg * 8) ^ (((ln >> 1) ^ mt) << 3);
                const bf16x8 ah = *reinterpret_cast<const bf16x8*>(&k_hi[mt * 16 + ln][col]);
                const bf16x8 al = *reinterpret_cast<const bf16x8*>(&k_lo[mt * 16 + ln][col]);
                s[mt] = __builtin_amdgcn_mfma_f32_16x16x32_bf16(ah, bh, s[mt], 0, 0, 0);
                s[mt] = __builtin_amdgcn_mfma_f32_16x16x32_bf16(ah, bl, s[mt], 0, 0, 0);
                s[mt] = __builtin_amdgcn_mfma_f32_16x16x32_bf16(al, bh, s[mt], 0, 0, 0);
            }
        }

        // ---- online softmax over m (column reduce across 4 lane groups) ----
        float tmax = -INFINITY;
        #pragma unroll
        for (int mt = 0; mt < 4; ++mt)
            #pragma unroll
            for (int r = 0; r < 4; ++r) tmax = fmaxf(tmax, s[mt][r]);
        tmax = fmaxf(tmax, __shfl_xor(tmax, 16));
        tmax = fmaxf(tmax, __shfl_xor(tmax, 32));

        const float mnew = fmaxf(run_max, tmax);
        const float corr = __expf(run_max - mnew);   // 0 on first iter

        float psum = 0.f;
        #pragma unroll
        for (int mt = 0; mt < 4; ++mt) {
            bf16x4 pp;
            #pragma unroll
            for (int r = 0; r < 4; ++r) {
                const float pv = __expf(s[mt][r] - mnew);
                psum += pv;
                pp[r] = (__bf16)pv;
            }
            // lane's 4 r-values are consecutive m-columns -> one b64 write
            *reinterpret_cast<bf16x4*>(
                &p_sm[wave][ln][(mt * 16 + lg * 4) ^ ((ln >> 1) << 3)]) = pp;
        }
        psum += __shfl_xor(psum, 16);
        psum += __shfl_xor(psum, 32);
        run_l   = run_l * corr + psum;
        run_max = mnew;

        #pragma unroll
        for (int ct = 0; ct < 4; ++ct) o[ct] *= corr;

        // ---- PV: O[c(64)][n(16)] += V[c][m] * P[m][n] ----
        // same-wave LDS write->read: DS ops complete in order within a wave
        #pragma unroll
        for (int ks = 0; ks < 2; ++ks) {
            const bf16x8 bp = *reinterpret_cast<const bf16x8*>(
                &p_sm[wave][ln][(ks * 32 + lg * 8) ^ ((ln >> 1) << 3)]);
            #pragma unroll
            for (int ct = 0; ct < 4; ++ct) {
                const int col = (ks * 32 + lg * 8) ^ (((ln >> 1) ^ ct) << 3);
                const bf16x8 av = *reinterpret_cast<const bf16x8*>(&v_sm[ct * 16 + ln][col]);
                o[ct] = __builtin_amdgcn_mfma_f32_16x16x32_bf16(av, bp, o[ct], 0, 0, 0);
            }
        }

        __syncthreads();   // all waves done reading k_hi/k_lo/v_sm
        if (it + 1 < tpb) {
            const int m0 = (t0 + it + 1) * MTILE;
            for (int i = tid; i < (MTILE * CC) / 4; i += WAVES * 64) {
                const int c  = i >> 4;
                const int m4 = (i & 15) * 4;
                const float4 v = *reinterpret_cast<const float4*>(yib + (size_t)c * MM + m0 + m4);
                const float fv[4] = {v.x, v.y, v.z, v.w};
                bf16x4 vv;
                #pragma unroll
                for (int j = 0; j < 4; ++j) {
                    const int m  = m4 + j;
                    const int sx = swz(m) << 3;
                    const __bf16 hi = (__bf16)fv[j];
                    k_hi[m][c ^ sx] = hi;
                    k_lo[m][c ^ sx] = (__bf16)(fv[j] - (float)hi);
                    vv[j] = hi;
                }
                *reinterpret_cast<bf16x4*>(&v_sm[c][m4 ^ (swz(c) << 3)]) = vv;
            }
        }
        __syncthreads();   // staged tile visible
    }

    // ---- epilogue ----
    if (FINAL) {
        const float inv = 1.f / run_l;
        #pragma unroll
        for (int ct = 0; ct < 4; ++ct) {
            #pragma unroll
            for (int r = 0; r < 4; ++r) {
                const int c = ct * 16 + lg * 4 + r;
                out[((size_t)b * CC + c) * MM + n_glob] = o[ct][r] * inv;
            }
        }
    } else {
        // unnormalized partial O + (running max, running sum) per query column
        const size_t pbase = (size_t)(b * nsplits + split) * CC * MM;
        #pragma unroll
        for (int ct = 0; ct < 4; ++ct) {
            #pragma unroll
            for (int r = 0; r < 4; ++r) {
                const int c = ct * 16 + lg * 4 + r;
                opart[pbase + (size_t)c * MM + n_glob] = o[ct][r];
            }
        }
        if (lg == 0) {   // run_max/run_l uniform across the 4 lane groups
            const size_t mb = ((size_t)(b * nsplits + split) * MM + n_glob) * 2;
            mlpart[mb]     = run_max;
            mlpart[mb + 1] = run_l;
        }
    }
}

// out[b,c,n] = sum_s Opart[b,s,c,n] * e^{m_s - M} / sum_s l_s * e^{m_s - M}
// S is a template parameter so ms[]/ls[] stay statically indexed (registers).
template<int S>
__global__ __launch_bounds__(256)
void attn_reduce(const float* __restrict__ opart, const float* __restrict__ mlpart,
                 float* __restrict__ out)
{
    const int gid = blockIdx.x * 256 + threadIdx.x;     // (b*CC + c)*MM + n
    if (gid >= BB * CC * MM) return;
    const int n  = gid % MM;
    const int bc = gid / MM;
    const int b  = bc / CC;
    const int c  = bc - b * CC;

    float ms[S], ls[S];
    float Mx = -INFINITY;
    #pragma unroll
    for (int s = 0; s < S; ++s) {
        const size_t mb = ((size_t)(b * S + s) * MM + n) * 2;
        ms[s] = mlpart[mb];
        ls[s] = mlpart[mb + 1];
        Mx = fmaxf(Mx, ms[s]);
    }
    float L = 0.f;
    #pragma unroll
    for (int s = 0; s < S; ++s) {
        ms[s] = __expf(ms[s] - Mx);
        L += ls[s] * ms[s];
    }
    float acc = 0.f;
    #pragma unroll
    for (int s = 0; s < S; ++s)
        acc += opart[((size_t)(b * S + s) * CC + c) * MM + n] * ms[s];
    out[gid] = acc / L;
}

extern "C" void kernel_launch(void* const* d_in, const int* in_sizes, int n_in,
                              void* d_out, int out_size, void* d_ws, size_t ws_size,
                              hipStream_t stream) {
    const float* yi = (const float*)d_in[0];   // feature_yi
    const float* pi = (const float*)d_in[1];   // feature_pi
    float* out = (float*)d_out;

    // workspace need for S splits: O partials (f32) + (m,l) per (b,s,n)
    auto need = [](int s) -> size_t {
        return (size_t)BB * s * CC * MM * 4 + (size_t)BB * s * MM * 2 * 4;
    };

    int S = 0;
    if (d_ws && ws_size >= need(8))      S = 8;   // 1536 blocks = 6/CU, 4 resident
    else if (d_ws && ws_size >= need(4)) S = 4;   // 768 blocks = 3/CU
    else if (d_ws && ws_size >= need(2)) S = 2;

    if (S == 0) {
        // fallback: original single-kernel path
        dim3 grid(MM / NBLK, 1, BB);
        attn_flash_split<true><<<grid, dim3(WAVES * 64), 0, stream>>>(
            yi, pi, out, nullptr, nullptr, 1);
    } else {
        float* opart  = (float*)d_ws;
        float* mlpart = opart + (size_t)BB * S * CC * MM;
        dim3 grid(MM / NBLK, S, BB);
        attn_flash_split<false><<<grid, dim3(WAVES * 64), 0, stream>>>(
            yi, pi, out, opart, mlpart, S);
        const int total = BB * CC * MM;
        const dim3 rg((total + 255) / 256), rb(256);
        if (S == 8)      attn_reduce<8><<<rg, rb, 0, stream>>>(opart, mlpart, out);
        else if (S == 4) attn_reduce<4><<<rg, rb, 0, stream>>>(opart, mlpart, out);
        else             attn_reduce<2><<<rg, rb, 0, stream>>>(opart, mlpart, out);
    }
}